// Round 2
// baseline (629.356 us; speedup 1.0000x reference)
//
#include <hip/hip_runtime.h>
#include <hip/hip_bf16.h>
#include <hip/hip_cooperative_groups.h>

namespace cg = cooperative_groups;

#define N_NODES 40000
#define N_EDGES 640000

#define GRID_BLOCKS 1024               // 4 blocks/CU at 256 thr — cooperative-safe
#define GRID_WAVES  (GRID_BLOCKS * 4)

typedef __attribute__((ext_vector_type(8))) short bfrag;   // 8 bf16
typedef __attribute__((ext_vector_type(4))) float ffrag;   // 4 fp32 acc

__device__ __forceinline__ float b2f_lo(unsigned u) {
    return __builtin_bit_cast(float, u << 16);
}
__device__ __forceinline__ float b2f_hi(unsigned u) {
    return __builtin_bit_cast(float, u & 0xffff0000u);
}
__device__ __forceinline__ unsigned short f2b(float f) {
    return __builtin_bit_cast(unsigned short, __float2bfloat16(f));
}

// ---------------- CSR scatter phase, D=64, bf16 in (R11 proven config) -------
// 8 nodes per wave (one per 8-lane group); lane owns 8 cols via one 16B uint4
// load (128B/row); unroll-4 (4 gathers in flight); contiguous stores.
// R12: edge-split across groups (+shfl) regressed. R13: column-split (16
// lanes/node, uint2) regressed +10us total — more TLP doesn't help, the
// 1KB-per-instruction uint4 shape is the local optimum. Do not touch.
template<bool OUT_F32>
__device__ __forceinline__ void scatter_phase(const unsigned short* __restrict__ T,
                                              const int* __restrict__ srcE,
                                              const int* __restrict__ rowptr,
                                              void* __restrict__ Hv,
                                              int gw, int lane) {
    const int g  = lane >> 3;            // group 0..7 -> node
    const int c8 = (lane & 7) * 8;       // cols c8..c8+7
    for (int w = gw; w < N_NODES / 8; w += GRID_WAVES) {
        const int node = w * 8 + g;
        const int e0 = rowptr[node], e1 = rowptr[node + 1];

        float a0 = 0.f, a1 = 0.f, a2 = 0.f, a3 = 0.f;
        float a4 = 0.f, a5 = 0.f, a6 = 0.f, a7 = 0.f;
        int e = e0;
        for (; e + 4 <= e1; e += 4) {
            int s0 = srcE[e], s1 = srcE[e + 1], s2 = srcE[e + 2], s3 = srcE[e + 3];
            uint4 t0 = *(const uint4*)(T + (size_t)s0 * 64 + c8);
            uint4 t1 = *(const uint4*)(T + (size_t)s1 * 64 + c8);
            uint4 t2 = *(const uint4*)(T + (size_t)s2 * 64 + c8);
            uint4 t3 = *(const uint4*)(T + (size_t)s3 * 64 + c8);
            a0 += (b2f_lo(t0.x) + b2f_lo(t1.x)) + (b2f_lo(t2.x) + b2f_lo(t3.x));
            a1 += (b2f_hi(t0.x) + b2f_hi(t1.x)) + (b2f_hi(t2.x) + b2f_hi(t3.x));
            a2 += (b2f_lo(t0.y) + b2f_lo(t1.y)) + (b2f_lo(t2.y) + b2f_lo(t3.y));
            a3 += (b2f_hi(t0.y) + b2f_hi(t1.y)) + (b2f_hi(t2.y) + b2f_hi(t3.y));
            a4 += (b2f_lo(t0.z) + b2f_lo(t1.z)) + (b2f_lo(t2.z) + b2f_lo(t3.z));
            a5 += (b2f_hi(t0.z) + b2f_hi(t1.z)) + (b2f_hi(t2.z) + b2f_hi(t3.z));
            a6 += (b2f_lo(t0.w) + b2f_lo(t1.w)) + (b2f_lo(t2.w) + b2f_lo(t3.w));
            a7 += (b2f_hi(t0.w) + b2f_hi(t1.w)) + (b2f_hi(t2.w) + b2f_hi(t3.w));
        }
        for (; e < e1; e++) {
            uint4 t0 = *(const uint4*)(T + (size_t)srcE[e] * 64 + c8);
            a0 += b2f_lo(t0.x); a1 += b2f_hi(t0.x);
            a2 += b2f_lo(t0.y); a3 += b2f_hi(t0.y);
            a4 += b2f_lo(t0.z); a5 += b2f_hi(t0.z);
            a6 += b2f_lo(t0.w); a7 += b2f_hi(t0.w);
        }

        if constexpr (OUT_F32) {
            float* q = (float*)Hv + (size_t)node * 64 + c8;
            *(float4*)q       = make_float4(a0, a1, a2, a3);
            *(float4*)(q + 4) = make_float4(a4, a5, a6, a7);
        } else {
            ushort4 o0, o1;
            o0.x = f2b(a0); o0.y = f2b(a1); o0.z = f2b(a2); o0.w = f2b(a3);
            o1.x = f2b(a4); o1.y = f2b(a5); o1.z = f2b(a6); o1.w = f2b(a7);
            unsigned short* q = (unsigned short*)Hv + (size_t)node * 64 + c8;
            *(ushort4*)q       = o0;
            *(ushort4*)(q + 4) = o1;
        }
    }
}

// ---------------- fused pipeline: ONE cooperative kernel, 4 grid syncs -------
// R14: 5 serial dispatches = 4 full drain/relaunch boundaries (prep's 32-block
// weight-chain was a 224-CU-idle tail). Fuse: phase0 rowptr+Wchain (parallel),
// phase1 MFMA gemm, phases 2-4 scatter. Also makes this kernel the top-1
// rocprof dispatch — per-phase costs finally visible in aggregate counters.
__global__ __launch_bounds__(256, 4) void fused_gin(
        const int* __restrict__ srcE, const int* __restrict__ dst,
        const float* __restrict__ X,
        const float* __restrict__ W1, const float* __restrict__ W2,
        const float* __restrict__ W3,
        float* __restrict__ out,
        unsigned short* __restrict__ T, unsigned short* __restrict__ H,
        int* __restrict__ rowptr, unsigned short* __restrict__ Wt123) {
    __shared__ float uS[4][128];
    cg::grid_group grid = cg::this_grid();
    const int bid  = blockIdx.x;
    const int tid  = threadIdx.x;
    const int wv   = tid >> 6;
    const int lane = tid & 63;
    const int gw   = bid * 4 + wv;       // global wave id, 0..4095

    // ---- phase 0a: rowptr via int4 adjacent-diff (threads 0..200000) ----
    {
        int i = bid * 256 + tid;
        if (i < N_EDGES / 4) {
            int e = i * 4;
            int4 d4 = *(const int4*)(dst + e);
            int dp = (e == 0) ? -1 : dst[e - 1];
            for (int n = dp + 1;   n <= d4.x; n++) rowptr[n] = e;
            for (int n = d4.x + 1; n <= d4.y; n++) rowptr[n] = e + 1;
            for (int n = d4.y + 1; n <= d4.z; n++) rowptr[n] = e + 2;
            for (int n = d4.z + 1; n <= d4.w; n++) rowptr[n] = e + 3;
        } else if (i < N_EDGES / 4 + N_NODES + 1) {
            int n = i - N_EDGES / 4;             // 0..N_NODES
            if (n > dst[N_EDGES - 1]) rowptr[n] = N_EDGES;
        }
    }

    // ---- phase 0b: weight chain Wt123 = bf16((W1 W2 W3)^T), last 32 blocks,
    //      one wave per k — now runs CONCURRENTLY with rowptr blocks ----
    if (bid >= GRID_BLOCKS - 32) {
        const int k = (bid - (GRID_BLOCKS - 32)) * 4 + wv;   // 0..127

        float u0 = 0.f, u1 = 0.f;
        const float* w1p = W1 + k * 128;
        const float* w2p = W2 + 2 * lane;
#pragma unroll 8
        for (int j = 0; j < 128; j++) {
            float a  = w1p[j];
            float2 w = *(const float2*)(w2p + (size_t)j * 128);
            u0 += a * w.x;
            u1 += a * w.y;
        }
        uS[wv][2 * lane]     = u0;
        uS[wv][2 * lane + 1] = u1;
        __syncthreads();

        float acc = 0.f;
        const float* w3p = W3 + lane;
#pragma unroll 8
        for (int l = 0; l < 128; l++)
            acc += uS[wv][l] * w3p[(size_t)l * 64];
        Wt123[lane * 128 + k] = f2b(acc);
    }

    grid.sync();

    // ---- phase 1: MFMA GEMM  T[N,64] = bf16( X[N,128] @ W123 ), 16 rows/wave
    if (gw < N_NODES / 16) {
        const int ml   = lane & 15;
        const int quad = lane >> 4;
        const int row0 = gw * 16;

        ffrag acc[4];
#pragma unroll
        for (int c = 0; c < 4; c++) acc[c] = (ffrag)0.f;

#pragma unroll
        for (int kb = 0; kb < 128; kb += 32) {
            const float* p = X + (size_t)(row0 + ml) * 128 + kb + quad * 8;
            float4 u0 = *(const float4*)p;
            float4 u1 = *(const float4*)(p + 4);
            bfrag a;
            a[0] = (short)f2b(u0.x); a[1] = (short)f2b(u0.y);
            a[2] = (short)f2b(u0.z); a[3] = (short)f2b(u0.w);
            a[4] = (short)f2b(u1.x); a[5] = (short)f2b(u1.y);
            a[6] = (short)f2b(u1.z); a[7] = (short)f2b(u1.w);
#pragma unroll
            for (int c = 0; c < 4; c++) {
                const int col = c * 16 + ml;
                bfrag b = *(const bfrag*)(Wt123 + (size_t)col * 128 + kb + quad * 8);
                acc[c] = __builtin_amdgcn_mfma_f32_16x16x32_bf16(a, b, acc[c], 0, 0, 0);
            }
        }
#pragma unroll
        for (int c = 0; c < 4; c++)
#pragma unroll
            for (int i = 0; i < 4; i++)
                T[(size_t)(row0 + quad * 4 + i) * 64 + c * 16 + ml] = f2b(acc[c][i]);
    }

    grid.sync();

    // ---- phases 2-4: S^3 via three scatters (grid.sync gives device-scope
    //      release/acquire, so H/T handoff is XCD-coherent) ----
    scatter_phase<false>(T, srcE, rowptr, H, gw, lane);
    grid.sync();
    scatter_phase<false>(H, srcE, rowptr, T, gw, lane);
    grid.sync();
    scatter_phase<true>(T, srcE, rowptr, out, gw, lane);
}

extern "C" void kernel_launch(void* const* d_in, const int* in_sizes, int n_in,
                              void* d_out, int out_size, void* d_ws, size_t ws_size,
                              hipStream_t stream) {
    const int*   src  = (const int*)d_in[0];
    const int*   dst  = (const int*)d_in[1];
    const float* feat = (const float*)d_in[2];
    const float* W1   = (const float*)d_in[3];
    const float* W2   = (const float*)d_in[4];
    const float* W3   = (const float*)d_in[5];
    float* out = (float*)d_out;

    // ws layout (bytes): T@0, H@5.25M, rowptr@10.5M, Wt123 after.
    char* wsb = (char*)d_ws;
    unsigned short* T     = (unsigned short*)wsb;
    unsigned short* H     = (unsigned short*)(wsb + (size_t)5505024);
    int* rowptr           = (int*)(wsb + (size_t)11010048);
    unsigned short* Wt123 = (unsigned short*)(wsb + (size_t)11010048 + 163968);

    // out = S^3 . (X @ (W1 W2 W3))  — S = segment-sum, commutes with W
    void* args[] = {(void*)&src, (void*)&dst, (void*)&feat,
                    (void*)&W1, (void*)&W2, (void*)&W3,
                    (void*)&out, (void*)&T, (void*)&H,
                    (void*)&rowptr, (void*)&Wt123};
    hipLaunchCooperativeKernel((void*)fused_gin, dim3(GRID_BLOCKS), dim3(256),
                               args, 0, stream);
}

// Round 3
// 134.383 us; speedup vs baseline: 4.6833x; 4.6833x over previous
//
#include <hip/hip_runtime.h>
#include <hip/hip_bf16.h>

#define N_NODES 40000
#define N_EDGES 640000

typedef __attribute__((ext_vector_type(8))) short bfrag;   // 8 bf16
typedef __attribute__((ext_vector_type(4))) float ffrag;   // 4 fp32 acc

__device__ __forceinline__ float b2f_lo(unsigned u) {
    return __builtin_bit_cast(float, u << 16);
}
__device__ __forceinline__ float b2f_hi(unsigned u) {
    return __builtin_bit_cast(float, u & 0xffff0000u);
}
__device__ __forceinline__ unsigned short f2b(float f) {
    return __builtin_bit_cast(unsigned short, __float2bfloat16(f));
}

// ---------------- prep: rowptr (int4 adjacent-diff) + Wt123 (k-parallel) ----
// blocks [0, RP): rowptr. Each thread handles 4 edges via one int4 load.
// blocks [RP, RP+32): weight chain, ONE WAVE PER k (128 waves):
//   u = W1[k,:] @ W2  (lane owns 2 cols, coalesced float2 loads)
//   Wt123[:,k] = u @ W3  (u via LDS broadcast, W3 rows coalesced)
#define RP_BLOCKS 782     // ceil((640000/4 + 40001)/256)
#define W_BLOCKS  32
__global__ __launch_bounds__(256) void prep(const int* __restrict__ dst,
                                            int* __restrict__ rowptr,
                                            const float* __restrict__ W1,
                                            const float* __restrict__ W2,
                                            const float* __restrict__ W3,
                                            unsigned short* __restrict__ Wt123) {
    __shared__ float uS[4][128];
    const int bid = blockIdx.x;
    if (bid < RP_BLOCKS) {
        int i = bid * 256 + threadIdx.x;
        if (i < N_EDGES / 4) {
            int e = i * 4;
            int4 d4 = *(const int4*)(dst + e);
            int dp = (e == 0) ? -1 : dst[e - 1];
            for (int n = dp + 1;   n <= d4.x; n++) rowptr[n] = e;
            for (int n = d4.x + 1; n <= d4.y; n++) rowptr[n] = e + 1;
            for (int n = d4.y + 1; n <= d4.z; n++) rowptr[n] = e + 2;
            for (int n = d4.z + 1; n <= d4.w; n++) rowptr[n] = e + 3;
        } else if (i < N_EDGES / 4 + N_NODES + 1) {
            int n = i - N_EDGES / 4;           // 0..N_NODES
            if (n > dst[N_EDGES - 1]) rowptr[n] = N_EDGES;
        }
        return;
    }

    // weight chain: one wave per k (128 waves) — latency hidden by TLP
    const int wv   = threadIdx.x >> 6;
    const int lane = threadIdx.x & 63;
    const int k    = (bid - RP_BLOCKS) * 4 + wv;   // 0..127

    float u0 = 0.f, u1 = 0.f;
    const float* w1p = W1 + k * 128;
    const float* w2p = W2 + 2 * lane;
#pragma unroll 8
    for (int j = 0; j < 128; j++) {
        float a  = w1p[j];
        float2 w = *(const float2*)(w2p + (size_t)j * 128);
        u0 += a * w.x;
        u1 += a * w.y;
    }
    uS[wv][2 * lane]     = u0;
    uS[wv][2 * lane + 1] = u1;
    __syncthreads();

    float acc = 0.f;
    const float* w3p = W3 + lane;
#pragma unroll 8
    for (int l = 0; l < 128; l++)
        acc += uS[wv][l] * w3p[(size_t)l * 64];
    Wt123[lane * 128 + k] = f2b(acc);
}

// ---------------- MFMA GEMM: T[N,64] = bf16( X[N,128] @ W123 ) ----------------
// Fragments straight from global (16B contiguous/lane); no LDS. 64 rows/block.
__global__ __launch_bounds__(256) void gemm_mfma64(const float* __restrict__ X,
                                                   const unsigned short* __restrict__ Wt,
                                                   unsigned short* __restrict__ Y) {
    const int wv   = threadIdx.x >> 6;
    const int lane = threadIdx.x & 63;
    const int ml   = lane & 15;
    const int quad = lane >> 4;
    const int row0 = blockIdx.x * 64 + wv * 16;

    ffrag acc[4];
#pragma unroll
    for (int c = 0; c < 4; c++) acc[c] = (ffrag)0.f;

#pragma unroll
    for (int kb = 0; kb < 128; kb += 32) {
        const float* p = X + (size_t)(row0 + ml) * 128 + kb + quad * 8;
        float4 u0 = *(const float4*)p;
        float4 u1 = *(const float4*)(p + 4);
        bfrag a;
        a[0] = (short)f2b(u0.x); a[1] = (short)f2b(u0.y);
        a[2] = (short)f2b(u0.z); a[3] = (short)f2b(u0.w);
        a[4] = (short)f2b(u1.x); a[5] = (short)f2b(u1.y);
        a[6] = (short)f2b(u1.z); a[7] = (short)f2b(u1.w);
#pragma unroll
        for (int c = 0; c < 4; c++) {
            const int col = c * 16 + ml;
            bfrag b = *(const bfrag*)(Wt + (size_t)col * 128 + kb + quad * 8);
            acc[c] = __builtin_amdgcn_mfma_f32_16x16x32_bf16(a, b, acc[c], 0, 0, 0);
        }
    }
#pragma unroll
    for (int c = 0; c < 4; c++)
#pragma unroll
        for (int i = 0; i < 4; i++)
            Y[(size_t)(row0 + quad * 4 + i) * 64 + c * 16 + ml] = f2b(acc[c][i]);
}

// ---------------- CSR scatter, D=64, bf16 in — R15: software-pipelined -------
// Lane layout: R11-proven 8 nodes/wave (8-lane groups), lane owns 8 cols via
// one 16B uint4 (128B/group-row). R12 (edge-split+shfl) and R13 (col-split
// uint2) both regressed — lane layout is settled. R14 (coop fusion) showed
// VALUBusy 2.2%: the cost is UN-HIDDEN LATENCY. R15 attacks the per-iteration
// serialization: the old loop was srcE-load -> wait -> gather -> wait -> acc
// per 4 edges (2 round trips, compiler can't rotate a divergent runtime-count
// loop). Hand-rotate depth 1: while accumulating quad i, quad i+1's gathers
// are already in flight and quad i+1's srcE loads issue before the accumulate.
// Tail: batched single-round-trip (predicated adds of 0) instead of serial.
template<bool OUT_F32>
__global__ __launch_bounds__(256) void scatter8(const unsigned short* __restrict__ T,
                                                const int* __restrict__ srcE,
                                                const int* __restrict__ rowptr,
                                                void* __restrict__ Hv) {
    const int wave = blockIdx.x * 4 + (threadIdx.x >> 6);
    const int lane = threadIdx.x & 63;
    const int g    = lane >> 3;          // group 0..7 -> node
    const int c8   = (lane & 7) * 8;     // cols c8..c8+7
    const int node = wave * 8 + g;
    if (node >= N_NODES) return;
    const int e0 = rowptr[node], e1 = rowptr[node + 1];

    float a0 = 0.f, a1 = 0.f, a2 = 0.f, a3 = 0.f;
    float a4 = 0.f, a5 = 0.f, a6 = 0.f, a7 = 0.f;

    int e = e0;
    uint4 t0, t1, t2, t3;
    bool have = (e + 4 <= e1);
    if (have) {                           // prologue: first quad's gathers
        int s0 = srcE[e], s1 = srcE[e + 1], s2 = srcE[e + 2], s3 = srcE[e + 3];
        t0 = *(const uint4*)(T + (size_t)s0 * 64 + c8);
        t1 = *(const uint4*)(T + (size_t)s1 * 64 + c8);
        t2 = *(const uint4*)(T + (size_t)s2 * 64 + c8);
        t3 = *(const uint4*)(T + (size_t)s3 * 64 + c8);
        e += 4;
    }
    while (have) {
        const bool next = (e + 4 <= e1);
        int s0, s1, s2, s3;
        if (next) {                       // issue next quad's indices first
            s0 = srcE[e]; s1 = srcE[e + 1]; s2 = srcE[e + 2]; s3 = srcE[e + 3];
        }
        // accumulate current quad (same pairwise order as R11 kernel)
        a0 += (b2f_lo(t0.x) + b2f_lo(t1.x)) + (b2f_lo(t2.x) + b2f_lo(t3.x));
        a1 += (b2f_hi(t0.x) + b2f_hi(t1.x)) + (b2f_hi(t2.x) + b2f_hi(t3.x));
        a2 += (b2f_lo(t0.y) + b2f_lo(t1.y)) + (b2f_lo(t2.y) + b2f_lo(t3.y));
        a3 += (b2f_hi(t0.y) + b2f_hi(t1.y)) + (b2f_hi(t2.y) + b2f_hi(t3.y));
        a4 += (b2f_lo(t0.z) + b2f_lo(t1.z)) + (b2f_lo(t2.z) + b2f_lo(t3.z));
        a5 += (b2f_hi(t0.z) + b2f_hi(t1.z)) + (b2f_hi(t2.z) + b2f_hi(t3.z));
        a6 += (b2f_lo(t0.w) + b2f_lo(t1.w)) + (b2f_lo(t2.w) + b2f_lo(t3.w));
        a7 += (b2f_hi(t0.w) + b2f_hi(t1.w)) + (b2f_hi(t2.w) + b2f_hi(t3.w));
        if (next) {                       // next quad's gathers go in flight
            t0 = *(const uint4*)(T + (size_t)s0 * 64 + c8);
            t1 = *(const uint4*)(T + (size_t)s1 * 64 + c8);
            t2 = *(const uint4*)(T + (size_t)s2 * 64 + c8);
            t3 = *(const uint4*)(T + (size_t)s3 * 64 + c8);
            e += 4;
        }
        have = next;
    }

    // tail (0..3 edges): batch all index loads + gathers, one round trip
    const int rem = e1 - e;
    if (rem > 0) {
        int s0 = srcE[e];
        int s1 = (rem > 1) ? srcE[e + 1] : s0;
        int s2 = (rem > 2) ? srcE[e + 2] : s0;
        uint4 q0 = *(const uint4*)(T + (size_t)s0 * 64 + c8);
        uint4 q1 = *(const uint4*)(T + (size_t)s1 * 64 + c8);
        uint4 q2 = *(const uint4*)(T + (size_t)s2 * 64 + c8);
        a0 += b2f_lo(q0.x); a1 += b2f_hi(q0.x);
        a2 += b2f_lo(q0.y); a3 += b2f_hi(q0.y);
        a4 += b2f_lo(q0.z); a5 += b2f_hi(q0.z);
        a6 += b2f_lo(q0.w); a7 += b2f_hi(q0.w);
        if (rem > 1) {
            a0 += b2f_lo(q1.x); a1 += b2f_hi(q1.x);
            a2 += b2f_lo(q1.y); a3 += b2f_hi(q1.y);
            a4 += b2f_lo(q1.z); a5 += b2f_hi(q1.z);
            a6 += b2f_lo(q1.w); a7 += b2f_hi(q1.w);
        }
        if (rem > 2) {
            a0 += b2f_lo(q2.x); a1 += b2f_hi(q2.x);
            a2 += b2f_lo(q2.y); a3 += b2f_hi(q2.y);
            a4 += b2f_lo(q2.z); a5 += b2f_hi(q2.z);
            a6 += b2f_lo(q2.w); a7 += b2f_hi(q2.w);
        }
    }

    if constexpr (OUT_F32) {
        float* q = (float*)Hv + (size_t)node * 64 + c8;
        *(float4*)q       = make_float4(a0, a1, a2, a3);
        *(float4*)(q + 4) = make_float4(a4, a5, a6, a7);
    } else {
        ushort4 o0, o1;
        o0.x = f2b(a0); o0.y = f2b(a1); o0.z = f2b(a2); o0.w = f2b(a3);
        o1.x = f2b(a4); o1.y = f2b(a5); o1.z = f2b(a6); o1.w = f2b(a7);
        unsigned short* q = (unsigned short*)Hv + (size_t)node * 64 + c8;
        *(ushort4*)q       = o0;
        *(ushort4*)(q + 4) = o1;
    }
}

extern "C" void kernel_launch(void* const* d_in, const int* in_sizes, int n_in,
                              void* d_out, int out_size, void* d_ws, size_t ws_size,
                              hipStream_t stream) {
    const int*   src  = (const int*)d_in[0];
    const int*   dst  = (const int*)d_in[1];
    const float* feat = (const float*)d_in[2];
    const float* W1   = (const float*)d_in[3];
    const float* W2   = (const float*)d_in[4];
    const float* W3   = (const float*)d_in[5];
    float* out = (float*)d_out;

    // ws layout (bytes): T@0, H@5.25M, rowptr@10.5M, Wt123 after.
    char* wsb = (char*)d_ws;
    unsigned short* T     = (unsigned short*)wsb;
    unsigned short* H     = (unsigned short*)(wsb + (size_t)5505024);
    int* rowptr           = (int*)(wsb + (size_t)11010048);
    unsigned short* Wt123 = (unsigned short*)(wsb + (size_t)11010048 + 163968);

    const int scatterBlocks = (N_NODES + 31) / 32;   // 1250 (8 nodes x 4 waves)

    // out = S^3 . (X @ (W1 W2 W3))  — S = segment-sum, commutes with W
    prep<<<RP_BLOCKS + W_BLOCKS, 256, 0, stream>>>(dst, rowptr, W1, W2, W3, Wt123);
    gemm_mfma64<<<625, 256, 0, stream>>>(feat, Wt123, T);
    scatter8<false><<<scatterBlocks, 256, 0, stream>>>(T, src, rowptr, H);
    scatter8<false><<<scatterBlocks, 256, 0, stream>>>(H, src, rowptr, T);
    scatter8<true><<<scatterBlocks, 256, 0, stream>>>(T, src, rowptr, out);
}

// Round 4
// 133.636 us; speedup vs baseline: 4.7095x; 1.0056x over previous
//
#include <hip/hip_runtime.h>
#include <hip/hip_bf16.h>

#define N_NODES 40000
#define N_EDGES 640000

typedef __attribute__((ext_vector_type(8))) short bfrag;   // 8 bf16
typedef __attribute__((ext_vector_type(4))) float ffrag;   // 4 fp32 acc

__device__ __forceinline__ float b2f_lo(unsigned u) {
    return __builtin_bit_cast(float, u << 16);
}
__device__ __forceinline__ float b2f_hi(unsigned u) {
    return __builtin_bit_cast(float, u & 0xffff0000u);
}
__device__ __forceinline__ unsigned short f2b(float f) {
    return __builtin_bit_cast(unsigned short, __float2bfloat16(f));
}

// ---------------- prep: rowptr (int4 adjacent-diff) + Wt123 (k-parallel) ----
#define RP_BLOCKS 782     // ceil((640000/4 + 40001)/256)
#define W_BLOCKS  32
__global__ __launch_bounds__(256) void prep(const int* __restrict__ dst,
                                            int* __restrict__ rowptr,
                                            const float* __restrict__ W1,
                                            const float* __restrict__ W2,
                                            const float* __restrict__ W3,
                                            unsigned short* __restrict__ Wt123) {
    __shared__ float uS[4][128];
    const int bid = blockIdx.x;
    if (bid < RP_BLOCKS) {
        int i = bid * 256 + threadIdx.x;
        if (i < N_EDGES / 4) {
            int e = i * 4;
            int4 d4 = *(const int4*)(dst + e);
            int dp = (e == 0) ? -1 : dst[e - 1];
            for (int n = dp + 1;   n <= d4.x; n++) rowptr[n] = e;
            for (int n = d4.x + 1; n <= d4.y; n++) rowptr[n] = e + 1;
            for (int n = d4.y + 1; n <= d4.z; n++) rowptr[n] = e + 2;
            for (int n = d4.z + 1; n <= d4.w; n++) rowptr[n] = e + 3;
        } else if (i < N_EDGES / 4 + N_NODES + 1) {
            int n = i - N_EDGES / 4;           // 0..N_NODES
            if (n > dst[N_EDGES - 1]) rowptr[n] = N_EDGES;
        }
        return;
    }

    // weight chain: one wave per k (128 waves) — latency hidden by TLP
    const int wv   = threadIdx.x >> 6;
    const int lane = threadIdx.x & 63;
    const int k    = (bid - RP_BLOCKS) * 4 + wv;   // 0..127

    float u0 = 0.f, u1 = 0.f;
    const float* w1p = W1 + k * 128;
    const float* w2p = W2 + 2 * lane;
#pragma unroll 8
    for (int j = 0; j < 128; j++) {
        float a  = w1p[j];
        float2 w = *(const float2*)(w2p + (size_t)j * 128);
        u0 += a * w.x;
        u1 += a * w.y;
    }
    uS[wv][2 * lane]     = u0;
    uS[wv][2 * lane + 1] = u1;
    __syncthreads();

    float acc = 0.f;
    const float* w3p = W3 + lane;
#pragma unroll 8
    for (int l = 0; l < 128; l++)
        acc += uS[wv][l] * w3p[(size_t)l * 64];
    Wt123[lane * 128 + k] = f2b(acc);
}

// ---------------- MFMA GEMM: T[N,64] = bf16( X[N,128] @ W123 ) ----------------
__global__ __launch_bounds__(256) void gemm_mfma64(const float* __restrict__ X,
                                                   const unsigned short* __restrict__ Wt,
                                                   unsigned short* __restrict__ Y) {
    const int wv   = threadIdx.x >> 6;
    const int lane = threadIdx.x & 63;
    const int ml   = lane & 15;
    const int quad = lane >> 4;
    const int row0 = blockIdx.x * 64 + wv * 16;

    ffrag acc[4];
#pragma unroll
    for (int c = 0; c < 4; c++) acc[c] = (ffrag)0.f;

#pragma unroll
    for (int kb = 0; kb < 128; kb += 32) {
        const float* p = X + (size_t)(row0 + ml) * 128 + kb + quad * 8;
        float4 u0 = *(const float4*)p;
        float4 u1 = *(const float4*)(p + 4);
        bfrag a;
        a[0] = (short)f2b(u0.x); a[1] = (short)f2b(u0.y);
        a[2] = (short)f2b(u0.z); a[3] = (short)f2b(u0.w);
        a[4] = (short)f2b(u1.x); a[5] = (short)f2b(u1.y);
        a[6] = (short)f2b(u1.z); a[7] = (short)f2b(u1.w);
#pragma unroll
        for (int c = 0; c < 4; c++) {
            const int col = c * 16 + ml;
            bfrag b = *(const bfrag*)(Wt + (size_t)col * 128 + kb + quad * 8);
            acc[c] = __builtin_amdgcn_mfma_f32_16x16x32_bf16(a, b, acc[c], 0, 0, 0);
        }
    }
#pragma unroll
    for (int c = 0; c < 4; c++)
#pragma unroll
        for (int i = 0; i < 4; i++)
            Y[(size_t)(row0 + quad * 4 + i) * 64 + c * 16 + ml] = f2b(acc[c][i]);
}

// ---------------- CSR scatter, D=64, bf16 in — R16: LDS-staged indices -------
// Lane layout: R11-proven 8 nodes/wave, lane owns 8 cols via uint4.
// R13 (+66% VMEM instr -> +3.3us/scatter) showed instr-count sensitivity;
// R15 (depth-1 rotation) bought only ~1us/scatter -> the srcE->gather serial
// chain remained. R16: block stages its contiguous srcE range (32 nodes,
// ~512 edges) into LDS coalesced, killing the in-loop index round trip AND
// halving in-loop VMEM instrs (8 -> 4 per quad). Gathers depth-2 pipelined
// (named regs A*/B*, no runtime indexing -> no scratch): acc(A) waits on
// loads issued two phases earlier. Accumulation order = quad-sequential,
// identical to R15.
#define IDX_LDS 2048
template<bool OUT_F32>
__global__ __launch_bounds__(256) void scatter8(const unsigned short* __restrict__ T,
                                                const int* __restrict__ srcE,
                                                const int* __restrict__ rowptr,
                                                void* __restrict__ Hv) {
    __shared__ int shIdx[IDX_LDS];
    const int tid   = threadIdx.x;
    const int node0 = blockIdx.x * 32;
    const int ebase = rowptr[node0];
    const int etop  = rowptr[node0 + 32];
    const int total = etop - ebase;

    const int lim = total < IDX_LDS ? total : IDX_LDS;
    for (int j = tid; j < lim; j += 256) shIdx[j] = srcE[ebase + j];
    __syncthreads();

    const int lane = tid & 63;
    const int g    = lane >> 3;          // group 0..7 -> node
    const int c8   = (lane & 7) * 8;     // cols c8..c8+7
    const int node = node0 + (tid >> 6) * 8 + g;
    const int e0 = rowptr[node], e1 = rowptr[node + 1];

    float a0 = 0.f, a1 = 0.f, a2 = 0.f, a3 = 0.f;
    float a4 = 0.f, a5 = 0.f, a6 = 0.f, a7 = 0.f;

#define GATH(s) (*(const uint4*)(T + (size_t)(s) * 64 + c8))
#define ACCQ(t0, t1, t2, t3)                                                  \
    do {                                                                      \
        a0 += (b2f_lo(t0.x) + b2f_lo(t1.x)) + (b2f_lo(t2.x) + b2f_lo(t3.x));  \
        a1 += (b2f_hi(t0.x) + b2f_hi(t1.x)) + (b2f_hi(t2.x) + b2f_hi(t3.x));  \
        a2 += (b2f_lo(t0.y) + b2f_lo(t1.y)) + (b2f_lo(t2.y) + b2f_lo(t3.y));  \
        a3 += (b2f_hi(t0.y) + b2f_hi(t1.y)) + (b2f_hi(t2.y) + b2f_hi(t3.y));  \
        a4 += (b2f_lo(t0.z) + b2f_lo(t1.z)) + (b2f_lo(t2.z) + b2f_lo(t3.z));  \
        a5 += (b2f_hi(t0.z) + b2f_hi(t1.z)) + (b2f_hi(t2.z) + b2f_hi(t3.z));  \
        a6 += (b2f_lo(t0.w) + b2f_lo(t1.w)) + (b2f_lo(t2.w) + b2f_lo(t3.w));  \
        a7 += (b2f_hi(t0.w) + b2f_hi(t1.w)) + (b2f_hi(t2.w) + b2f_hi(t3.w));  \
    } while (0)

    int e = e0;
    if (total <= IDX_LDS) {
        // ---- fast path: indices from LDS, depth-2 gather pipeline ----
        uint4 A0, A1, A2, A3, B0, B1, B2, B3;
        bool haveA = false, haveB = false;
        if (e + 4 <= e1) {
            int o = e - ebase;
            A0 = GATH(shIdx[o]);     A1 = GATH(shIdx[o + 1]);
            A2 = GATH(shIdx[o + 2]); A3 = GATH(shIdx[o + 3]);
            e += 4; haveA = true;
            if (e + 4 <= e1) {
                o = e - ebase;
                B0 = GATH(shIdx[o]);     B1 = GATH(shIdx[o + 1]);
                B2 = GATH(shIdx[o + 2]); B3 = GATH(shIdx[o + 3]);
                e += 4; haveB = true;
            }
        }
        while (haveA) {
            ACCQ(A0, A1, A2, A3);
            if (e + 4 <= e1) {
                int o = e - ebase;
                A0 = GATH(shIdx[o]);     A1 = GATH(shIdx[o + 1]);
                A2 = GATH(shIdx[o + 2]); A3 = GATH(shIdx[o + 3]);
                e += 4;
            } else haveA = false;
            if (!haveB) break;
            ACCQ(B0, B1, B2, B3);
            if (e + 4 <= e1) {
                int o = e - ebase;
                B0 = GATH(shIdx[o]);     B1 = GATH(shIdx[o + 1]);
                B2 = GATH(shIdx[o + 2]); B3 = GATH(shIdx[o + 3]);
                e += 4;
            } else haveB = false;
        }
        // tail 0..3 edges, batched single round trip
        const int rem = e1 - e;
        if (rem > 0) {
            int o = e - ebase;
            int s0 = shIdx[o];
            int s1 = (rem > 1) ? shIdx[o + 1] : s0;
            int s2 = (rem > 2) ? shIdx[o + 2] : s0;
            uint4 q0 = GATH(s0), q1 = GATH(s1), q2 = GATH(s2);
            a0 += b2f_lo(q0.x); a1 += b2f_hi(q0.x);
            a2 += b2f_lo(q0.y); a3 += b2f_hi(q0.y);
            a4 += b2f_lo(q0.z); a5 += b2f_hi(q0.z);
            a6 += b2f_lo(q0.w); a7 += b2f_hi(q0.w);
            if (rem > 1) {
                a0 += b2f_lo(q1.x); a1 += b2f_hi(q1.x);
                a2 += b2f_lo(q1.y); a3 += b2f_hi(q1.y);
                a4 += b2f_lo(q1.z); a5 += b2f_hi(q1.z);
                a6 += b2f_lo(q1.w); a7 += b2f_hi(q1.w);
            }
            if (rem > 2) {
                a0 += b2f_lo(q2.x); a1 += b2f_hi(q2.x);
                a2 += b2f_lo(q2.y); a3 += b2f_hi(q2.y);
                a4 += b2f_lo(q2.z); a5 += b2f_hi(q2.z);
                a6 += b2f_lo(q2.w); a7 += b2f_hi(q2.w);
            }
        }
    } else {
        // ---- overflow fallback (statistically unreachable): R15 loop ----
        uint4 t0, t1, t2, t3;
        bool have = (e + 4 <= e1);
        if (have) {
            int s0 = srcE[e], s1 = srcE[e + 1], s2 = srcE[e + 2], s3 = srcE[e + 3];
            t0 = GATH(s0); t1 = GATH(s1); t2 = GATH(s2); t3 = GATH(s3);
            e += 4;
        }
        while (have) {
            const bool next = (e + 4 <= e1);
            int s0, s1, s2, s3;
            if (next) { s0 = srcE[e]; s1 = srcE[e + 1]; s2 = srcE[e + 2]; s3 = srcE[e + 3]; }
            ACCQ(t0, t1, t2, t3);
            if (next) {
                t0 = GATH(s0); t1 = GATH(s1); t2 = GATH(s2); t3 = GATH(s3);
                e += 4;
            }
            have = next;
        }
        const int rem = e1 - e;
        if (rem > 0) {
            int s0 = srcE[e];
            int s1 = (rem > 1) ? srcE[e + 1] : s0;
            int s2 = (rem > 2) ? srcE[e + 2] : s0;
            uint4 q0 = GATH(s0), q1 = GATH(s1), q2 = GATH(s2);
            a0 += b2f_lo(q0.x); a1 += b2f_hi(q0.x);
            a2 += b2f_lo(q0.y); a3 += b2f_hi(q0.y);
            a4 += b2f_lo(q0.z); a5 += b2f_hi(q0.z);
            a6 += b2f_lo(q0.w); a7 += b2f_hi(q0.w);
            if (rem > 1) {
                a0 += b2f_lo(q1.x); a1 += b2f_hi(q1.x);
                a2 += b2f_lo(q1.y); a3 += b2f_hi(q1.y);
                a4 += b2f_lo(q1.z); a5 += b2f_hi(q1.z);
                a6 += b2f_lo(q1.w); a7 += b2f_hi(q1.w);
            }
            if (rem > 2) {
                a0 += b2f_lo(q2.x); a1 += b2f_hi(q2.x);
                a2 += b2f_lo(q2.y); a3 += b2f_hi(q2.y);
                a4 += b2f_lo(q2.z); a5 += b2f_hi(q2.z);
                a6 += b2f_lo(q2.w); a7 += b2f_hi(q2.w);
            }
        }
    }
#undef GATH
#undef ACCQ

    if constexpr (OUT_F32) {
        float* q = (float*)Hv + (size_t)node * 64 + c8;
        *(float4*)q       = make_float4(a0, a1, a2, a3);
        *(float4*)(q + 4) = make_float4(a4, a5, a6, a7);
    } else {
        ushort4 o0, o1;
        o0.x = f2b(a0); o0.y = f2b(a1); o0.z = f2b(a2); o0.w = f2b(a3);
        o1.x = f2b(a4); o1.y = f2b(a5); o1.z = f2b(a6); o1.w = f2b(a7);
        unsigned short* q = (unsigned short*)Hv + (size_t)node * 64 + c8;
        *(ushort4*)q       = o0;
        *(ushort4*)(q + 4) = o1;
    }
}

extern "C" void kernel_launch(void* const* d_in, const int* in_sizes, int n_in,
                              void* d_out, int out_size, void* d_ws, size_t ws_size,
                              hipStream_t stream) {
    const int*   src  = (const int*)d_in[0];
    const int*   dst  = (const int*)d_in[1];
    const float* feat = (const float*)d_in[2];
    const float* W1   = (const float*)d_in[3];
    const float* W2   = (const float*)d_in[4];
    const float* W3   = (const float*)d_in[5];
    float* out = (float*)d_out;

    // ws layout (bytes): T@0, H@5.25M, rowptr@10.5M, Wt123 after.
    char* wsb = (char*)d_ws;
    unsigned short* T     = (unsigned short*)wsb;
    unsigned short* H     = (unsigned short*)(wsb + (size_t)5505024);
    int* rowptr           = (int*)(wsb + (size_t)11010048);
    unsigned short* Wt123 = (unsigned short*)(wsb + (size_t)11010048 + 163968);

    const int scatterBlocks = (N_NODES + 31) / 32;   // 1250 (8 nodes x 4 waves)

    // out = S^3 . (X @ (W1 W2 W3))  — S = segment-sum, commutes with W
    prep<<<RP_BLOCKS + W_BLOCKS, 256, 0, stream>>>(dst, rowptr, W1, W2, W3, Wt123);
    gemm_mfma64<<<625, 256, 0, stream>>>(feat, Wt123, T);
    scatter8<false><<<scatterBlocks, 256, 0, stream>>>(T, src, rowptr, H);
    scatter8<false><<<scatterBlocks, 256, 0, stream>>>(H, src, rowptr, T);
    scatter8<true><<<scatterBlocks, 256, 0, stream>>>(T, src, rowptr, out);
}